// Round 1
// 504.707 us; speedup vs baseline: 1.0092x; 1.0092x over previous
//
#include <hip/hip_runtime.h>
#include <hip/hip_bf16.h>
#include <cstdint>

typedef float  f32x4 __attribute__((ext_vector_type(4)));
typedef short  s16x4 __attribute__((ext_vector_type(4)));
typedef short  s16x8 __attribute__((ext_vector_type(8)));
typedef __bf16 bf16x8 __attribute__((ext_vector_type(8)));
typedef unsigned int u32x2 __attribute__((ext_vector_type(2)));
typedef unsigned int u32x4 __attribute__((ext_vector_type(4)));

static __device__ __forceinline__ unsigned short f2bf(float f) {
  union { float f; unsigned u; } v; v.f = f;
  unsigned r = v.u + 0x7fffu + ((v.u >> 16) & 1u);   // RTNE
  return (unsigned short)(r >> 16);
}

// packed fp32 pair -> 2x bf16 in one VALU op (RTNE), lo -> bits[15:0]
static __device__ __forceinline__ unsigned pk2(float lo, float hi) {
  unsigned r;
  asm("v_cvt_pk_bf16_f32 %0, %1, %2" : "=v"(r) : "v"(lo), "v"(hi));
  return r;
}

static __device__ __forceinline__ f32x4 mfma16(bf16x8 a, bf16x8 b, f32x4 c) {
  return __builtin_amdgcn_mfma_f32_16x16x32_bf16(a, b, c, 0, 0, 0);
}

// ---------------------------------------------------------------------------
// k_mlp: fused per-ROI 2-layer MLP. Grid 512 = 64 ROIs x 8 HID-slices of 64.
// Tile: M=128 (batch) x N=64 (HID slice), K=2048 in 32 steps of BK=64.
// Epilogue: h = relu(C + b1slice) -> P = h @ W2slice -> atomicAdd(m1, P/64).
// ~51 KB LDS -> 2 blocks/CU for barrier-drain overlap.
// Staging converts fp32->bf16 via v_cvt_pk_bf16_f32 (1 op / 2 elems) to keep
// the inter-barrier storeTile off the VALU critical path.
// ---------------------------------------------------------------------------
__global__ __launch_bounds__(256)
void k_mlp(const float* __restrict__ X, const float* __restrict__ W1,
           const float* __restrict__ b1, const float* __restrict__ W2,
           float* __restrict__ m1)
{
  __shared__ short lds_a[128 * 72];   // [m][k] bf16, k padded 64->72
  __shared__ short lds_b[64 * 72];    // [n][k] bf16
  __shared__ short lds_h[128 * 72];   // layer2 A: [m][kh] bf16
  __shared__ short lds_w2[32 * 72];   // layer2 B: [o][kh] bf16 (o>=20 zero)
  __shared__ float biasS[64];

  const int bid = blockIdx.x;
  // XCD swizzle: the 8 c-slices of one r land on the same XCD
  const int r = (bid & 7) + ((bid >> 6) << 3);
  const int c = (bid >> 3) & 7;

  const float* xr = X + (long)r * (128 * 2048);
  const float* wr = W1 + (long)r * (2048 * 512) + c * 64;
  const float* bp = b1 + (long)r * 512 + c * 64;

  const int t = threadIdx.x;
  const int lane = t & 63;
  const int w = t >> 6;

  if (t < 64) biasS[t] = bp[t];

  // staging maps (BK=64)
  const int aRow = t >> 2;             // 0..63 (+64 for second group)
  const int aCol = (t & 3) * 4;        // within-row float offset, +16j
  const int bn   = t & 63;
  const int bk0  = w * 8;              // k-chunk base: 0,8,16,24 (+32 for g=1)

  f32x4 aR[2][4];
  float bR[2][8];

  auto loadTile = [&](int ks) {
    const float* xp = xr + (long)aRow * 2048 + ks * 64 + aCol;
#pragma unroll
    for (int j = 0; j < 4; j++) {
      aR[0][j] = *(const f32x4*)(xp + 16 * j);
      aR[1][j] = *(const f32x4*)(xp + 64 * 2048 + 16 * j);
    }
    const float* wp = wr + (long)(ks * 64 + bk0) * 512 + bn;
#pragma unroll
    for (int g = 0; g < 2; g++)
#pragma unroll
      for (int j = 0; j < 8; j++)
        bR[g][j] = wp[(long)(g * 32 + j) * 512];
  };

  auto storeTile = [&]() {
#pragma unroll
    for (int g = 0; g < 2; g++)
#pragma unroll
      for (int j = 0; j < 4; j++) {
        u32x2 v;
        v[0] = pk2(aR[g][j][0], aR[g][j][1]);
        v[1] = pk2(aR[g][j][2], aR[g][j][3]);
        *(u32x2*)&lds_a[(aRow + 64 * g) * 72 + aCol + 16 * j] = v;
      }
#pragma unroll
    for (int g = 0; g < 2; g++) {
      u32x4 v;
      v[0] = pk2(bR[g][0], bR[g][1]);
      v[1] = pk2(bR[g][2], bR[g][3]);
      v[2] = pk2(bR[g][4], bR[g][5]);
      v[3] = pk2(bR[g][6], bR[g][7]);
      *(u32x4*)&lds_b[bn * 72 + bk0 + g * 32] = v;
    }
  };

  // 4 waves as 2(m) x 2(n): each wave 64m x 32n; per step 4x2x2 MFMAs
  const int wm = w & 1, wn = w >> 1;
  const int mBase = wm * 64, nBase = wn * 32;
  const int lm = lane & 15, lg = lane >> 4;

  f32x4 acc[4][2];
#pragma unroll
  for (int i = 0; i < 4; i++)
#pragma unroll
    for (int j = 0; j < 2; j++) acc[i][j] = f32x4{0.f, 0.f, 0.f, 0.f};

  loadTile(0);
  for (int ks = 0; ks < 32; ks++) {
    __syncthreads();
    storeTile();
    __syncthreads();
    if (ks + 1 < 32) loadTile(ks + 1);
    bf16x8 af[2][4], bfr[2][2];
#pragma unroll
    for (int g = 0; g < 2; g++) {
#pragma unroll
      for (int i = 0; i < 4; i++)
        af[g][i] = *(const bf16x8*)&lds_a[(mBase + i * 16 + lm) * 72 + g * 32 + lg * 8];
#pragma unroll
      for (int j = 0; j < 2; j++)
        bfr[g][j] = *(const bf16x8*)&lds_b[(nBase + j * 16 + lm) * 72 + g * 32 + lg * 8];
    }
#pragma unroll
    for (int mi = 0; mi < 4; mi++)
#pragma unroll
      for (int ni = 0; ni < 2; ni++) {
        acc[mi][ni] = mfma16(af[0][mi], bfr[0][ni], acc[mi][ni]);
        acc[mi][ni] = mfma16(af[1][mi], bfr[1][ni], acc[mi][ni]);
      }
  }

  // h = relu(acc + b1) -> lds_h (bf16, A-layout [m][kh])
#pragma unroll
  for (int mi = 0; mi < 4; mi++)
#pragma unroll
    for (int ni = 0; ni < 2; ni++) {
      const int col = nBase + ni * 16 + lm;
      const float bv = biasS[col];
#pragma unroll
      for (int i = 0; i < 4; i++) {
        const int row = mBase + mi * 16 + lg * 4 + i;
        float v = acc[mi][ni][i] + bv;
        v = v > 0.f ? v : 0.f;
        lds_h[row * 72 + col] = (short)f2bf(v);
      }
    }
  // stage W2 slice [kh 0..63][o 0..19] -> lds_w2[o][kh], zero-pad o>=20
  {
    const float* w2r = W2 + (long)r * (512 * 20) + (long)c * 64 * 20;
#pragma unroll
    for (int i = 0; i < 8; i++) {
      const int idx = t * 8 + i;            // 0..2047
      const int o = idx >> 6, kh = idx & 63;
      const float v = (o < 20) ? w2r[(long)kh * 20 + o] : 0.f;
      lds_w2[o * 72 + kh] = (short)f2bf(v);
    }
  }
  __syncthreads();
  // layer-2: wave w -> m rows [w*32, w*32+32), o 0..31, K=64 (2 steps)
  f32x4 acc2[2][2];
#pragma unroll
  for (int i = 0; i < 2; i++)
#pragma unroll
    for (int j = 0; j < 2; j++) acc2[i][j] = f32x4{0.f, 0.f, 0.f, 0.f};
#pragma unroll
  for (int ks2 = 0; ks2 < 2; ks2++) {
    bf16x8 a0 = *(const bf16x8*)&lds_h[(w * 32 + lm) * 72 + ks2 * 32 + lg * 8];
    bf16x8 a1 = *(const bf16x8*)&lds_h[(w * 32 + 16 + lm) * 72 + ks2 * 32 + lg * 8];
    bf16x8 b0 = *(const bf16x8*)&lds_w2[lm * 72 + ks2 * 32 + lg * 8];
    bf16x8 b1v = *(const bf16x8*)&lds_w2[(16 + lm) * 72 + ks2 * 32 + lg * 8];
    acc2[0][0] = mfma16(a0, b0, acc2[0][0]);
    acc2[0][1] = mfma16(a0, b1v, acc2[0][1]);
    acc2[1][0] = mfma16(a1, b0, acc2[1][0]);
    acc2[1][1] = mfma16(a1, b1v, acc2[1][1]);
  }
#pragma unroll
  for (int mi = 0; mi < 2; mi++)
#pragma unroll
    for (int ni = 0; ni < 2; ni++)
#pragma unroll
      for (int i = 0; i < 4; i++) {
        const int m = w * 32 + mi * 16 + lg * 4 + i;
        const int o = ni * 16 + lm;
        if (o < 20)
          atomicAdd(&m1[m * 20 + o], acc2[mi][ni][i] * (1.f / 64.f));
      }
}

// ---------------------------------------------------------------------------
// gemm_n64: out[:, c*64 : c*64+64] = act(X[128,K] @ W[K,N] + bias)
// M=128 x N=64 tiles, BK=64, grid = N/64. Same wave layout as k_mlp.
// ---------------------------------------------------------------------------
template<int RELU>
__global__ __launch_bounds__(256)
void gemm_n64(const float* __restrict__ X, int ldx,
              const float* __restrict__ W, int ldw,
              const float* __restrict__ bias,
              float* __restrict__ out, int ldo, int kSteps)
{
  __shared__ short lds_a[128 * 72];
  __shared__ short lds_b[64 * 72];
  __shared__ float biasS[64];

  const int c = blockIdx.x;
  const int t = threadIdx.x;
  const int lane = t & 63;
  const int w = t >> 6;

  if (t < 64) biasS[t] = bias[c * 64 + t];

  const int aRow = t >> 2;
  const int aCol = (t & 3) * 4;
  const int bn   = t & 63;
  const int bk0  = w * 8;

  f32x4 aR[2][4];
  float bR[2][8];

  auto loadTile = [&](int ks) {
    const float* xp = X + (long)aRow * ldx + ks * 64 + aCol;
#pragma unroll
    for (int j = 0; j < 4; j++) {
      aR[0][j] = *(const f32x4*)(xp + 16 * j);
      aR[1][j] = *(const f32x4*)(xp + (long)64 * ldx + 16 * j);
    }
    const float* wp = W + (long)(ks * 64 + bk0) * ldw + c * 64 + bn;
#pragma unroll
    for (int g = 0; g < 2; g++)
#pragma unroll
      for (int j = 0; j < 8; j++)
        bR[g][j] = wp[(long)(g * 32 + j) * ldw];
  };

  auto storeTile = [&]() {
#pragma unroll
    for (int g = 0; g < 2; g++)
#pragma unroll
      for (int j = 0; j < 4; j++) {
        u32x2 v;
        v[0] = pk2(aR[g][j][0], aR[g][j][1]);
        v[1] = pk2(aR[g][j][2], aR[g][j][3]);
        *(u32x2*)&lds_a[(aRow + 64 * g) * 72 + aCol + 16 * j] = v;
      }
#pragma unroll
    for (int g = 0; g < 2; g++) {
      u32x4 v;
      v[0] = pk2(bR[g][0], bR[g][1]);
      v[1] = pk2(bR[g][2], bR[g][3]);
      v[2] = pk2(bR[g][4], bR[g][5]);
      v[3] = pk2(bR[g][6], bR[g][7]);
      *(u32x4*)&lds_b[bn * 72 + bk0 + g * 32] = v;
    }
  };

  const int wm = w & 1, wn = w >> 1;
  const int mBase = wm * 64, nBase = wn * 32;
  const int lm = lane & 15, lg = lane >> 4;

  f32x4 acc[4][2];
#pragma unroll
  for (int i = 0; i < 4; i++)
#pragma unroll
    for (int j = 0; j < 2; j++) acc[i][j] = f32x4{0.f, 0.f, 0.f, 0.f};

  loadTile(0);
  for (int ks = 0; ks < kSteps; ks++) {
    __syncthreads();
    storeTile();
    __syncthreads();
    if (ks + 1 < kSteps) loadTile(ks + 1);
    bf16x8 af[2][4], bfr[2][2];
#pragma unroll
    for (int g = 0; g < 2; g++) {
#pragma unroll
      for (int i = 0; i < 4; i++)
        af[g][i] = *(const bf16x8*)&lds_a[(mBase + i * 16 + lm) * 72 + g * 32 + lg * 8];
#pragma unroll
      for (int j = 0; j < 2; j++)
        bfr[g][j] = *(const bf16x8*)&lds_b[(nBase + j * 16 + lm) * 72 + g * 32 + lg * 8];
    }
#pragma unroll
    for (int mi = 0; mi < 4; mi++)
#pragma unroll
      for (int ni = 0; ni < 2; ni++) {
        acc[mi][ni] = mfma16(af[0][mi], bfr[0][ni], acc[mi][ni]);
        acc[mi][ni] = mfma16(af[1][mi], bfr[1][ni], acc[mi][ni]);
      }
  }

  float* outp = out + c * 64;
#pragma unroll
  for (int mi = 0; mi < 4; mi++)
#pragma unroll
    for (int ni = 0; ni < 2; ni++) {
      const int col = nBase + ni * 16 + lm;
      const float bv = biasS[col];
#pragma unroll
      for (int i = 0; i < 4; i++) {
        const int row = mBase + mi * 16 + lg * 4 + i;
        float v = acc[mi][ni][i] + bv;
        if (RELU) v = v > 0.f ? v : 0.f;
        outp[(long)row * ldo + col] = v;
      }
    }
}

// m1 init: mean over r of b2; k_mlp atomically adds the rest.
__global__ void k_init_m1(const float* __restrict__ b2, float* __restrict__ m1) {
  const int i = blockIdx.x * blockDim.x + threadIdx.x;
  if (i >= 128 * 20) return;
  const int o = i % 20;
  float s = 0.f;
  for (int r = 0; r < 64; r++) s += b2[r * 20 + o];
  m1[i] = s * (1.f / 64.f);
}

// small FC, K fully unrolled (all W loads in flight) for latency
template<int K, int RELU>
__global__ void k_fc_small(const float* __restrict__ in, const float* __restrict__ Wt,
                           const float* __restrict__ bias, float* __restrict__ out,
                           int N)
{
  const int i = blockIdx.x * blockDim.x + threadIdx.x;
  const int b = i / N;
  if (b >= 128) return;
  const int j = i - b * N;
  float s = bias[j];
  const float* ip = in + (long)b * K;
#pragma unroll
  for (int k = 0; k < K; k++) s += ip[k] * Wt[k * N + j];
  out[i] = (RELU && s < 0.f) ? 0.f : s;
}

extern "C" void kernel_launch(void* const* d_in, const int* in_sizes, int n_in,
                              void* d_out, int out_size, void* d_ws, size_t ws_size,
                              hipStream_t stream)
{
  const float* x   = (const float*)d_in[0];
  const float* W1  = (const float*)d_in[3];
  const float* b1  = (const float*)d_in[4];
  const float* W2  = (const float*)d_in[5];
  const float* b2  = (const float*)d_in[6];
  const float* Wg1 = (const float*)d_in[7];
  const float* bg1 = (const float*)d_in[8];
  const float* Wg2 = (const float*)d_in[9];
  const float* bg2 = (const float*)d_in[10];
  const float* Wf1 = (const float*)d_in[11];
  const float* bf1 = (const float*)d_in[12];
  const float* Wf2 = (const float*)d_in[13];
  const float* bf2 = (const float*)d_in[14];
  const float* Wo  = (const float*)d_in[15];
  const float* bo  = (const float*)d_in[16];
  float* out = (float*)d_out;

  float* ws = (float*)d_ws;
  float* m1 = ws;            // 2560 floats
  float* g1 = ws + 4096;     // 8192
  float* g2 = ws + 16384;    // 16384
  float* y1 = ws + 32768;    // 65536
  float* y2 = ws + 98304;    // 131072

  k_init_m1<<<10, 256, 0, stream>>>(b2, m1);
  // dominant: per-ROI 2-layer MLP, 64 ROIs x 8 HID-slices
  k_mlp<<<512, 256, 0, stream>>>(x, W1, b1, W2, m1);
  // collapsed-GCN + FC chain
  k_fc_small<20, 1><<<32, 256, 0, stream>>>(m1, Wg1, bg1, g1, 64);
  k_fc_small<64, 1><<<64, 256, 0, stream>>>(g1, Wg2, bg2, g2, 128);
  gemm_n64<1><<<8,   256, 0, stream>>>(g2, 128,  Wf1, 512,  bf1, y1, 512, 2);
  gemm_n64<1><<<16,  256, 0, stream>>>(y1, 512,  Wf2, 1024, bf2, y2, 1024, 8);
  gemm_n64<0><<<100, 256, 0, stream>>>(y2, 1024, Wo,  6400, bo,  out, 6400, 16);
}

// Round 3
// 498.077 us; speedup vs baseline: 1.0226x; 1.0133x over previous
//
#include <hip/hip_runtime.h>
#include <hip/hip_bf16.h>
#include <cstdint>

typedef float  f32x4 __attribute__((ext_vector_type(4)));
typedef short  s16x4 __attribute__((ext_vector_type(4)));
typedef short  s16x8 __attribute__((ext_vector_type(8)));
typedef __bf16 bf16x8 __attribute__((ext_vector_type(8)));
typedef unsigned int u32x2 __attribute__((ext_vector_type(2)));
typedef unsigned int u32x4 __attribute__((ext_vector_type(4)));

static __device__ __forceinline__ unsigned short f2bf(float f) {
  union { float f; unsigned u; } v; v.f = f;
  unsigned r = v.u + 0x7fffu + ((v.u >> 16) & 1u);   // RTNE
  return (unsigned short)(r >> 16);
}

// packed fp32 pair -> 2x bf16 in one VALU op (RTNE), lo -> bits[15:0]
static __device__ __forceinline__ unsigned pk2(float lo, float hi) {
  unsigned r;
  asm("v_cvt_pk_bf16_f32 %0, %1, %2" : "=v"(r) : "v"(lo), "v"(hi));
  return r;
}

static __device__ __forceinline__ f32x4 mfma16(bf16x8 a, bf16x8 b, f32x4 c) {
  return __builtin_amdgcn_mfma_f32_16x16x32_bf16(a, b, c, 0, 0, 0);
}

// ---------------------------------------------------------------------------
// k_mlp: fused per-ROI 2-layer MLP.
// M=128 (batch) x N=128 (HID slice) per block, 512 thr (8 waves as 2m x 4n),
// grid 256 = 64 ROIs x 4 HID-slices. Halves the X sharing fan-out (4 blocks
// re-read each X panel instead of 8) to cut L2 misses on X against the
// streaming W1 traffic. XCD swizzle keeps the 4 c-slices of one ROI on one
// XCD. K=2048 in 32 steps of BK=64. Epilogue: h = relu(C + b1) -> lds_h,
// P = h @ W2slice -> atomicAdd(m1, P/64). LDS ~79 KB.
// ---------------------------------------------------------------------------
__global__ __launch_bounds__(512)
void k_mlp(const float* __restrict__ X, const float* __restrict__ W1,
           const float* __restrict__ b1, const float* __restrict__ W2,
           float* __restrict__ m1)
{
  __shared__ short lds_a[128 * 72];    // [m][k] bf16, k padded 64->72
  __shared__ short lds_b[128 * 72];    // [n][k] bf16
  __shared__ short lds_h[128 * 136];   // layer2 A: [m][kh] bf16, kh 128->136
  __shared__ short lds_w2[32 * 136];   // layer2 B: [o][kh] bf16 (o>=20 zero)
  __shared__ float biasS[128];

  const int bid = blockIdx.x;
  // XCD swizzle: the 4 c-slices of one r land on the same XCD (bid mod 8)
  const int r = (bid & 7) + ((bid >> 5) << 3);
  const int c = (bid >> 3) & 3;

  const float* xr = X + (long)r * (128 * 2048);
  const float* wr = W1 + (long)r * (2048 * 512) + c * 128;
  const float* bp = b1 + (long)r * 512 + c * 128;

  const int t = threadIdx.x;
  const int lane = t & 63;
  const int w = t >> 6;                // 0..7

  if (t < 128) biasS[t] = bp[t];

  // staging maps (BK=64)
  const int aRow = t >> 2;             // 0..127
  const int aCol = (t & 3) * 4;        // within-row float offset, +16j
  const int bn   = t & 127;            // 0..127
  const int bk0  = (t >> 7) * 8;       // k-chunk base: 0,8,16,24 (+32 for g=1)

  f32x4 aR[4];
  float bR[2][8];

  auto loadTile = [&](int ks) {
    const float* xp = xr + (long)aRow * 2048 + ks * 64 + aCol;
#pragma unroll
    for (int j = 0; j < 4; j++)
      aR[j] = *(const f32x4*)(xp + 16 * j);
    const float* wp = wr + (long)(ks * 64 + bk0) * 512 + bn;
#pragma unroll
    for (int g = 0; g < 2; g++)
#pragma unroll
      for (int j = 0; j < 8; j++)
        bR[g][j] = wp[(long)(g * 32 + j) * 512];
  };

  auto storeTile = [&]() {
#pragma unroll
    for (int j = 0; j < 4; j++) {
      u32x2 v;
      v[0] = pk2(aR[j][0], aR[j][1]);
      v[1] = pk2(aR[j][2], aR[j][3]);
      *(u32x2*)&lds_a[aRow * 72 + aCol + 16 * j] = v;
    }
#pragma unroll
    for (int g = 0; g < 2; g++) {
      u32x4 v;
      v[0] = pk2(bR[g][0], bR[g][1]);
      v[1] = pk2(bR[g][2], bR[g][3]);
      v[2] = pk2(bR[g][4], bR[g][5]);
      v[3] = pk2(bR[g][6], bR[g][7]);
      *(u32x4*)&lds_b[bn * 72 + bk0 + g * 32] = v;
    }
  };

  // 8 waves as 2(m) x 4(n): each wave 64m x 32n; per step 4x2x2 MFMAs
  const int wm = w & 1, wn = w >> 1;
  const int mBase = wm * 64, nBase = wn * 32;
  const int lm = lane & 15, lg = lane >> 4;

  f32x4 acc[4][2];
#pragma unroll
  for (int i = 0; i < 4; i++)
#pragma unroll
    for (int j = 0; j < 2; j++) acc[i][j] = f32x4{0.f, 0.f, 0.f, 0.f};

  loadTile(0);
  for (int ks = 0; ks < 32; ks++) {
    __syncthreads();
    storeTile();
    __syncthreads();
    if (ks + 1 < 32) loadTile(ks + 1);
    bf16x8 af[2][4], bfr[2][2];
#pragma unroll
    for (int g = 0; g < 2; g++) {
#pragma unroll
      for (int i = 0; i < 4; i++)
        af[g][i] = *(const bf16x8*)&lds_a[(mBase + i * 16 + lm) * 72 + g * 32 + lg * 8];
#pragma unroll
      for (int j = 0; j < 2; j++)
        bfr[g][j] = *(const bf16x8*)&lds_b[(nBase + j * 16 + lm) * 72 + g * 32 + lg * 8];
    }
#pragma unroll
    for (int mi = 0; mi < 4; mi++)
#pragma unroll
      for (int ni = 0; ni < 2; ni++) {
        acc[mi][ni] = mfma16(af[0][mi], bfr[0][ni], acc[mi][ni]);
        acc[mi][ni] = mfma16(af[1][mi], bfr[1][ni], acc[mi][ni]);
      }
  }

  // h = relu(acc + b1) -> lds_h (bf16, A-layout [m][kh], kh = HID-slice col)
#pragma unroll
  for (int mi = 0; mi < 4; mi++)
#pragma unroll
    for (int ni = 0; ni < 2; ni++) {
      const int col = nBase + ni * 16 + lm;      // 0..127
      const float bv = biasS[col];
#pragma unroll
      for (int i = 0; i < 4; i++) {
        const int row = mBase + mi * 16 + lg * 4 + i;
        float v = acc[mi][ni][i] + bv;
        v = v > 0.f ? v : 0.f;
        lds_h[row * 136 + col] = (short)f2bf(v);
      }
    }
  // stage W2 slice [kh 0..127][o 0..19] -> lds_w2[o][kh], zero-pad o>=20
  {
    const float* w2r = W2 + (long)r * (512 * 20) + (long)(c * 128) * 20;
#pragma unroll
    for (int i = 0; i < 8; i++) {
      const int idx = t * 8 + i;            // 0..4095
      const int o = idx >> 7, kh = idx & 127;
      const float v = (o < 20) ? w2r[(long)kh * 20 + o] : 0.f;
      lds_w2[o * 136 + kh] = (short)f2bf(v);
    }
  }
  __syncthreads();
  // layer-2: wave w -> m rows [w*16, w*16+16), o 0..31, K=128 (4 steps)
  f32x4 acc2[2];
  acc2[0] = f32x4{0.f, 0.f, 0.f, 0.f};
  acc2[1] = f32x4{0.f, 0.f, 0.f, 0.f};
#pragma unroll
  for (int ks2 = 0; ks2 < 4; ks2++) {
    bf16x8 a0 = *(const bf16x8*)&lds_h[(w * 16 + lm) * 136 + ks2 * 32 + lg * 8];
    bf16x8 b0 = *(const bf16x8*)&lds_w2[lm * 136 + ks2 * 32 + lg * 8];
    bf16x8 b1v = *(const bf16x8*)&lds_w2[(16 + lm) * 136 + ks2 * 32 + lg * 8];
    acc2[0] = mfma16(a0, b0, acc2[0]);
    acc2[1] = mfma16(a0, b1v, acc2[1]);
  }
#pragma unroll
  for (int ni = 0; ni < 2; ni++)
#pragma unroll
    for (int i = 0; i < 4; i++) {
      const int m = w * 16 + lg * 4 + i;
      const int o = ni * 16 + lm;
      if (o < 20)
        atomicAdd(&m1[m * 20 + o], acc2[ni][i] * (1.f / 64.f));
    }
}

// ---------------------------------------------------------------------------
// gemm_n64: out[:, c*64 : c*64+64] = act(X[128,K] @ W[K,N] + bias)
// M=128 x N=64 tiles, BK=64, grid = N/64.
// ---------------------------------------------------------------------------
template<int RELU>
__global__ __launch_bounds__(256)
void gemm_n64(const float* __restrict__ X, int ldx,
              const float* __restrict__ W, int ldw,
              const float* __restrict__ bias,
              float* __restrict__ out, int ldo, int kSteps)
{
  __shared__ short lds_a[128 * 72];
  __shared__ short lds_b[64 * 72];
  __shared__ float biasS[64];

  const int c = blockIdx.x;
  const int t = threadIdx.x;
  const int lane = t & 63;
  const int w = t >> 6;

  if (t < 64) biasS[t] = bias[c * 64 + t];

  const int aRow = t >> 2;
  const int aCol = (t & 3) * 4;
  const int bn   = t & 63;
  const int bk0  = w * 8;

  f32x4 aR[2][4];
  float bR[2][8];

  auto loadTile = [&](int ks) {
    const float* xp = X + (long)aRow * ldx + ks * 64 + aCol;
#pragma unroll
    for (int j = 0; j < 4; j++) {
      aR[0][j] = *(const f32x4*)(xp + 16 * j);
      aR[1][j] = *(const f32x4*)(xp + (long)64 * ldx + 16 * j);
    }
    const float* wp = W + (long)(ks * 64 + bk0) * ldw + c * 64 + bn;
#pragma unroll
    for (int g = 0; g < 2; g++)
#pragma unroll
      for (int j = 0; j < 8; j++)
        bR[g][j] = wp[(long)(g * 32 + j) * ldw];
  };

  auto storeTile = [&]() {
#pragma unroll
    for (int g = 0; g < 2; g++)
#pragma unroll
      for (int j = 0; j < 4; j++) {
        u32x2 v;
        v[0] = pk2(aR[g][j][0], aR[g][j][1]);
        v[1] = pk2(aR[g][j][2], aR[g][j][3]);
        *(u32x2*)&lds_a[(aRow + 64 * g) * 72 + aCol + 16 * j] = v;
      }
#pragma unroll
    for (int g = 0; g < 2; g++) {
      u32x4 v;
      v[0] = pk2(bR[g][0], bR[g][1]);
      v[1] = pk2(bR[g][2], bR[g][3]);
      v[2] = pk2(bR[g][4], bR[g][5]);
      v[3] = pk2(bR[g][6], bR[g][7]);
      *(u32x4*)&lds_b[bn * 72 + bk0 + g * 32] = v;
    }
  };

  const int wm = w & 1, wn = w >> 1;
  const int mBase = wm * 64, nBase = wn * 32;
  const int lm = lane & 15, lg = lane >> 4;

  f32x4 acc[4][2];
#pragma unroll
  for (int i = 0; i < 4; i++)
#pragma unroll
    for (int j = 0; j < 2; j++) acc[i][j] = f32x4{0.f, 0.f, 0.f, 0.f};

  loadTile(0);
  for (int ks = 0; ks < kSteps; ks++) {
    __syncthreads();
    storeTile();
    __syncthreads();
    if (ks + 1 < kSteps) loadTile(ks + 1);
    bf16x8 af[2][4], bfr[2][2];
#pragma unroll
    for (int g = 0; g < 2; g++) {
#pragma unroll
      for (int i = 0; i < 4; i++)
        af[g][i] = *(const bf16x8*)&lds_a[(mBase + i * 16 + lm) * 72 + g * 32 + lg * 8];
#pragma unroll
      for (int j = 0; j < 2; j++)
        bfr[g][j] = *(const bf16x8*)&lds_b[(nBase + j * 16 + lm) * 72 + g * 32 + lg * 8];
    }
#pragma unroll
    for (int mi = 0; mi < 4; mi++)
#pragma unroll
      for (int ni = 0; ni < 2; ni++) {
        acc[mi][ni] = mfma16(af[0][mi], bfr[0][ni], acc[mi][ni]);
        acc[mi][ni] = mfma16(af[1][mi], bfr[1][ni], acc[mi][ni]);
      }
  }

  float* outp = out + c * 64;
#pragma unroll
  for (int mi = 0; mi < 4; mi++)
#pragma unroll
    for (int ni = 0; ni < 2; ni++) {
      const int col = nBase + ni * 16 + lm;
      const float bv = biasS[col];
#pragma unroll
      for (int i = 0; i < 4; i++) {
        const int row = mBase + mi * 16 + lg * 4 + i;
        float v = acc[mi][ni][i] + bv;
        if (RELU) v = v > 0.f ? v : 0.f;
        outp[(long)row * ldo + col] = v;
      }
    }
}

// m1 init: mean over r of b2; k_mlp atomically adds the rest.
__global__ void k_init_m1(const float* __restrict__ b2, float* __restrict__ m1) {
  const int i = blockIdx.x * blockDim.x + threadIdx.x;
  if (i >= 128 * 20) return;
  const int o = i % 20;
  float s = 0.f;
  for (int r = 0; r < 64; r++) s += b2[r * 20 + o];
  m1[i] = s * (1.f / 64.f);
}

// small FC, K fully unrolled (all W loads in flight) for latency
template<int K, int RELU>
__global__ void k_fc_small(const float* __restrict__ in, const float* __restrict__ Wt,
                           const float* __restrict__ bias, float* __restrict__ out,
                           int N)
{
  const int i = blockIdx.x * blockDim.x + threadIdx.x;
  const int b = i / N;
  if (b >= 128) return;
  const int j = i - b * N;
  float s = bias[j];
  const float* ip = in + (long)b * K;
#pragma unroll
  for (int k = 0; k < K; k++) s += ip[k] * Wt[k * N + j];
  out[i] = (RELU && s < 0.f) ? 0.f : s;
}

extern "C" void kernel_launch(void* const* d_in, const int* in_sizes, int n_in,
                              void* d_out, int out_size, void* d_ws, size_t ws_size,
                              hipStream_t stream)
{
  const float* x   = (const float*)d_in[0];
  const float* W1  = (const float*)d_in[3];
  const float* b1  = (const float*)d_in[4];
  const float* W2  = (const float*)d_in[5];
  const float* b2  = (const float*)d_in[6];
  const float* Wg1 = (const float*)d_in[7];
  const float* bg1 = (const float*)d_in[8];
  const float* Wg2 = (const float*)d_in[9];
  const float* bg2 = (const float*)d_in[10];
  const float* Wf1 = (const float*)d_in[11];
  const float* bf1 = (const float*)d_in[12];
  const float* Wf2 = (const float*)d_in[13];
  const float* bf2 = (const float*)d_in[14];
  const float* Wo  = (const float*)d_in[15];
  const float* bo  = (const float*)d_in[16];
  float* out = (float*)d_out;

  float* ws = (float*)d_ws;
  float* m1 = ws;            // 2560 floats
  float* g1 = ws + 4096;     // 8192
  float* g2 = ws + 16384;    // 16384
  float* y1 = ws + 32768;    // 65536
  float* y2 = ws + 98304;    // 131072

  k_init_m1<<<10, 256, 0, stream>>>(b2, m1);
  // dominant: per-ROI 2-layer MLP, 64 ROIs x 4 HID-slices of 128
  k_mlp<<<256, 512, 0, stream>>>(x, W1, b1, W2, m1);
  // collapsed-GCN + FC chain
  k_fc_small<20, 1><<<32, 256, 0, stream>>>(m1, Wg1, bg1, g1, 64);
  k_fc_small<64, 1><<<64, 256, 0, stream>>>(g1, Wg2, bg2, g2, 128);
  gemm_n64<1><<<8,   256, 0, stream>>>(g2, 128,  Wf1, 512,  bf1, y1, 512, 2);
  gemm_n64<1><<<16,  256, 0, stream>>>(y1, 512,  Wf2, 1024, bf2, y2, 1024, 8);
  gemm_n64<0><<<100, 256, 0, stream>>>(y2, 1024, Wo,  6400, bo,  out, 6400, 16);
}

// Round 4
// 495.613 us; speedup vs baseline: 1.0277x; 1.0050x over previous
//
#include <hip/hip_runtime.h>
#include <hip/hip_bf16.h>
#include <cstdint>

typedef float  f32x4 __attribute__((ext_vector_type(4)));
typedef short  s16x4 __attribute__((ext_vector_type(4)));
typedef short  s16x8 __attribute__((ext_vector_type(8)));
typedef __bf16 bf16x8 __attribute__((ext_vector_type(8)));
typedef unsigned int u32x2 __attribute__((ext_vector_type(2)));
typedef unsigned int u32x4 __attribute__((ext_vector_type(4)));

static __device__ __forceinline__ unsigned short f2bf(float f) {
  union { float f; unsigned u; } v; v.f = f;
  unsigned r = v.u + 0x7fffu + ((v.u >> 16) & 1u);   // RTNE
  return (unsigned short)(r >> 16);
}

// packed fp32 pair -> 2x bf16 in one VALU op (RTNE), lo -> bits[15:0]
static __device__ __forceinline__ unsigned pk2(float lo, float hi) {
  unsigned r;
  asm("v_cvt_pk_bf16_f32 %0, %1, %2" : "=v"(r) : "v"(lo), "v"(hi));
  return r;
}

static __device__ __forceinline__ f32x4 mfma16(bf16x8 a, bf16x8 b, f32x4 c) {
  return __builtin_amdgcn_mfma_f32_16x16x32_bf16(a, b, c, 0, 0, 0);
}

// ---------------------------------------------------------------------------
// k_mlp: fused per-ROI 2-layer MLP.
// Round-4: M=64 (batch half) x N=128 (HID slice) per block, 256 thr (4 waves
// as 1m x 4n), grid 512 = 64 r x 4 c x 2 mHalf -> exactly 2 blocks/CU, so
// one block's barrier drain overlaps the twin block's compute (the overlap
// R3's 1-block/CU config lost). The mHalf twins read the SAME W1 slice and
// sit on the same XCD (rLo = bid&7), so the duplicate W1 read is an L2 hit —
// HBM stays at the W1-once minimum. X fan-out stays 4 (L3-resident anyway).
// K=2048 in 32 steps of BK=64. Epilogue: h = relu(C+b1) -> lds_h,
// P = h @ W2slice -> atomicAdd(m1, P/64). LDS ~54 KB.
// ---------------------------------------------------------------------------
__global__ __launch_bounds__(256)
void k_mlp(const float* __restrict__ X, const float* __restrict__ W1,
           const float* __restrict__ b1, const float* __restrict__ W2,
           float* __restrict__ m1)
{
  __shared__ short lds_a[64 * 72];     // [m][k] bf16, k padded 64->72
  __shared__ short lds_b[128 * 72];    // [n][k] bf16
  __shared__ short lds_h[64 * 136];    // layer2 A: [m][kh] bf16, kh 128->136
  __shared__ short lds_w2[32 * 136];   // layer2 B: [o][kh] bf16 (o>=20 zero)
  __shared__ float biasS[128];

  const int bid = blockIdx.x;
  // bid = rLo(3b) | c(2b) | mHalf(1b) | rHi(3b): all slices of one r on one
  // XCD; mHalf twins 32 bids apart -> co-resident, share W1 slice via L2.
  const int rLo   = bid & 7;
  const int c     = (bid >> 3) & 3;
  const int mHalf = (bid >> 5) & 1;
  const int r     = rLo + ((bid >> 6) << 3);

  const float* xr = X + (long)r * (128 * 2048) + (long)mHalf * (64 * 2048);
  const float* wr = W1 + (long)r * (2048 * 512) + c * 128;
  const float* bp = b1 + (long)r * 512 + c * 128;

  const int t = threadIdx.x;
  const int lane = t & 63;
  const int w = t >> 6;                // 0..3

  if (t < 128) biasS[t] = bp[t];

  // staging maps (BK=64)
  const int aRow = t >> 2;             // 0..63
  const int aCol = (t & 3) * 4;        // within-row float offset, +16j
  const int bn   = t & 127;            // 0..127
  const int bk0  = (t >> 7) * 8;       // 0 or 8; g*16 spans the rest

  f32x4 aR[4];
  float bR[4][8];

  auto loadTile = [&](int ks) {
    const float* xp = xr + (long)aRow * 2048 + ks * 64 + aCol;
#pragma unroll
    for (int j = 0; j < 4; j++)
      aR[j] = *(const f32x4*)(xp + 16 * j);
    const float* wp = wr + (long)(ks * 64 + bk0) * 512 + bn;
#pragma unroll
    for (int g = 0; g < 4; g++)
#pragma unroll
      for (int j = 0; j < 8; j++)
        bR[g][j] = wp[(long)(g * 16 + j) * 512];
  };

  auto storeTile = [&]() {
#pragma unroll
    for (int j = 0; j < 4; j++) {
      u32x2 v;
      v[0] = pk2(aR[j][0], aR[j][1]);
      v[1] = pk2(aR[j][2], aR[j][3]);
      *(u32x2*)&lds_a[aRow * 72 + aCol + 16 * j] = v;
    }
#pragma unroll
    for (int g = 0; g < 4; g++) {
      u32x4 v;
      v[0] = pk2(bR[g][0], bR[g][1]);
      v[1] = pk2(bR[g][2], bR[g][3]);
      v[2] = pk2(bR[g][4], bR[g][5]);
      v[3] = pk2(bR[g][6], bR[g][7]);
      *(u32x4*)&lds_b[bn * 72 + bk0 + g * 16] = v;
    }
  };

  // 4 waves as 1(m) x 4(n): each wave 64m x 32n; per step 4x2x2 MFMAs
  const int nBase = w * 32;
  const int lm = lane & 15, lg = lane >> 4;

  f32x4 acc[4][2];
#pragma unroll
  for (int i = 0; i < 4; i++)
#pragma unroll
    for (int j = 0; j < 2; j++) acc[i][j] = f32x4{0.f, 0.f, 0.f, 0.f};

  loadTile(0);
  for (int ks = 0; ks < 32; ks++) {
    __syncthreads();
    storeTile();
    __syncthreads();
    if (ks + 1 < 32) loadTile(ks + 1);
    bf16x8 af[2][4], bfr[2][2];
#pragma unroll
    for (int g = 0; g < 2; g++) {
#pragma unroll
      for (int i = 0; i < 4; i++)
        af[g][i] = *(const bf16x8*)&lds_a[(i * 16 + lm) * 72 + g * 32 + lg * 8];
#pragma unroll
      for (int j = 0; j < 2; j++)
        bfr[g][j] = *(const bf16x8*)&lds_b[(nBase + j * 16 + lm) * 72 + g * 32 + lg * 8];
    }
#pragma unroll
    for (int mi = 0; mi < 4; mi++)
#pragma unroll
      for (int ni = 0; ni < 2; ni++) {
        acc[mi][ni] = mfma16(af[0][mi], bfr[0][ni], acc[mi][ni]);
        acc[mi][ni] = mfma16(af[1][mi], bfr[1][ni], acc[mi][ni]);
      }
  }

  // h = relu(acc + b1) -> lds_h (bf16, A-layout [m][kh], kh = HID-slice col)
#pragma unroll
  for (int mi = 0; mi < 4; mi++)
#pragma unroll
    for (int ni = 0; ni < 2; ni++) {
      const int col = nBase + ni * 16 + lm;      // 0..127
      const float bv = biasS[col];
#pragma unroll
      for (int i = 0; i < 4; i++) {
        const int row = mi * 16 + lg * 4 + i;    // 0..63
        float v = acc[mi][ni][i] + bv;
        v = v > 0.f ? v : 0.f;
        lds_h[row * 136 + col] = (short)f2bf(v);
      }
    }
  // stage W2 slice [kh 0..127][o 0..19] -> lds_w2[o][kh], zero-pad o>=20
  {
    const float* w2r = W2 + (long)r * (512 * 20) + (long)(c * 128) * 20;
#pragma unroll
    for (int i = 0; i < 16; i++) {
      const int idx = t * 16 + i;           // 0..4095
      const int o = idx >> 7, kh = idx & 127;
      const float v = (o < 20) ? w2r[(long)kh * 20 + o] : 0.f;
      lds_w2[o * 136 + kh] = (short)f2bf(v);
    }
  }
  __syncthreads();
  // layer-2: wave w -> m rows [w*16, w*16+16), o 0..31, K=128 (4 steps)
  f32x4 acc2[2];
  acc2[0] = f32x4{0.f, 0.f, 0.f, 0.f};
  acc2[1] = f32x4{0.f, 0.f, 0.f, 0.f};
#pragma unroll
  for (int ks2 = 0; ks2 < 4; ks2++) {
    bf16x8 a0 = *(const bf16x8*)&lds_h[(w * 16 + lm) * 136 + ks2 * 32 + lg * 8];
    bf16x8 b0 = *(const bf16x8*)&lds_w2[lm * 136 + ks2 * 32 + lg * 8];
    bf16x8 b1v = *(const bf16x8*)&lds_w2[(16 + lm) * 136 + ks2 * 32 + lg * 8];
    acc2[0] = mfma16(a0, b0, acc2[0]);
    acc2[1] = mfma16(a0, b1v, acc2[1]);
  }
#pragma unroll
  for (int ni = 0; ni < 2; ni++)
#pragma unroll
    for (int i = 0; i < 4; i++) {
      const int m = mHalf * 64 + w * 16 + lg * 4 + i;
      const int o = ni * 16 + lm;
      if (o < 20)
        atomicAdd(&m1[m * 20 + o], acc2[ni][i] * (1.f / 64.f));
    }
}

// ---------------------------------------------------------------------------
// gemm_n64: out[:, c*64 : c*64+64] = act(X[128,K] @ W[K,N] + bias)
// M=128 x N=64 tiles, BK=64, grid = N/64.
// ---------------------------------------------------------------------------
template<int RELU>
__global__ __launch_bounds__(256)
void gemm_n64(const float* __restrict__ X, int ldx,
              const float* __restrict__ W, int ldw,
              const float* __restrict__ bias,
              float* __restrict__ out, int ldo, int kSteps)
{
  __shared__ short lds_a[128 * 72];
  __shared__ short lds_b[64 * 72];
  __shared__ float biasS[64];

  const int c = blockIdx.x;
  const int t = threadIdx.x;
  const int lane = t & 63;
  const int w = t >> 6;

  if (t < 64) biasS[t] = bias[c * 64 + t];

  const int aRow = t >> 2;
  const int aCol = (t & 3) * 4;
  const int bn   = t & 63;
  const int bk0  = w * 8;

  f32x4 aR[2][4];
  float bR[2][8];

  auto loadTile = [&](int ks) {
    const float* xp = X + (long)aRow * ldx + ks * 64 + aCol;
#pragma unroll
    for (int j = 0; j < 4; j++) {
      aR[0][j] = *(const f32x4*)(xp + 16 * j);
      aR[1][j] = *(const f32x4*)(xp + (long)64 * ldx + 16 * j);
    }
    const float* wp = W + (long)(ks * 64 + bk0) * ldw + c * 64 + bn;
#pragma unroll
    for (int g = 0; g < 2; g++)
#pragma unroll
      for (int j = 0; j < 8; j++)
        bR[g][j] = wp[(long)(g * 32 + j) * ldw];
  };

  auto storeTile = [&]() {
#pragma unroll
    for (int g = 0; g < 2; g++)
#pragma unroll
      for (int j = 0; j < 4; j++) {
        u32x2 v;
        v[0] = pk2(aR[g][j][0], aR[g][j][1]);
        v[1] = pk2(aR[g][j][2], aR[g][j][3]);
        *(u32x2*)&lds_a[(aRow + 64 * g) * 72 + aCol + 16 * j] = v;
      }
#pragma unroll
    for (int g = 0; g < 2; g++) {
      u32x4 v;
      v[0] = pk2(bR[g][0], bR[g][1]);
      v[1] = pk2(bR[g][2], bR[g][3]);
      v[2] = pk2(bR[g][4], bR[g][5]);
      v[3] = pk2(bR[g][6], bR[g][7]);
      *(u32x4*)&lds_b[bn * 72 + bk0 + g * 32] = v;
    }
  };

  const int wm = w & 1, wn = w >> 1;
  const int mBase = wm * 64, nBase = wn * 32;
  const int lm = lane & 15, lg = lane >> 4;

  f32x4 acc[4][2];
#pragma unroll
  for (int i = 0; i < 4; i++)
#pragma unroll
    for (int j = 0; j < 2; j++) acc[i][j] = f32x4{0.f, 0.f, 0.f, 0.f};

  loadTile(0);
  for (int ks = 0; ks < kSteps; ks++) {
    __syncthreads();
    storeTile();
    __syncthreads();
    if (ks + 1 < kSteps) loadTile(ks + 1);
    bf16x8 af[2][4], bfr[2][2];
#pragma unroll
    for (int g = 0; g < 2; g++) {
#pragma unroll
      for (int i = 0; i < 4; i++)
        af[g][i] = *(const bf16x8*)&lds_a[(mBase + i * 16 + lm) * 72 + g * 32 + lg * 8];
#pragma unroll
      for (int j = 0; j < 2; j++)
        bfr[g][j] = *(const bf16x8*)&lds_b[(nBase + j * 16 + lm) * 72 + g * 32 + lg * 8];
    }
#pragma unroll
    for (int mi = 0; mi < 4; mi++)
#pragma unroll
      for (int ni = 0; ni < 2; ni++) {
        acc[mi][ni] = mfma16(af[0][mi], bfr[0][ni], acc[mi][ni]);
        acc[mi][ni] = mfma16(af[1][mi], bfr[1][ni], acc[mi][ni]);
      }
  }

  float* outp = out + c * 64;
#pragma unroll
  for (int mi = 0; mi < 4; mi++)
#pragma unroll
    for (int ni = 0; ni < 2; ni++) {
      const int col = nBase + ni * 16 + lm;
      const float bv = biasS[col];
#pragma unroll
      for (int i = 0; i < 4; i++) {
        const int row = mBase + mi * 16 + lg * 4 + i;
        float v = acc[mi][ni][i] + bv;
        if (RELU) v = v > 0.f ? v : 0.f;
        outp[(long)row * ldo + col] = v;
      }
    }
}

// m1 init: mean over r of b2; k_mlp atomically adds the rest.
__global__ void k_init_m1(const float* __restrict__ b2, float* __restrict__ m1) {
  const int i = blockIdx.x * blockDim.x + threadIdx.x;
  if (i >= 128 * 20) return;
  const int o = i % 20;
  float s = 0.f;
  for (int r = 0; r < 64; r++) s += b2[r * 20 + o];
  m1[i] = s * (1.f / 64.f);
}

// small FC, K fully unrolled (all W loads in flight) for latency
template<int K, int RELU>
__global__ void k_fc_small(const float* __restrict__ in, const float* __restrict__ Wt,
                           const float* __restrict__ bias, float* __restrict__ out,
                           int N)
{
  const int i = blockIdx.x * blockDim.x + threadIdx.x;
  const int b = i / N;
  if (b >= 128) return;
  const int j = i - b * N;
  float s = bias[j];
  const float* ip = in + (long)b * K;
#pragma unroll
  for (int k = 0; k < K; k++) s += ip[k] * Wt[k * N + j];
  out[i] = (RELU && s < 0.f) ? 0.f : s;
}

extern "C" void kernel_launch(void* const* d_in, const int* in_sizes, int n_in,
                              void* d_out, int out_size, void* d_ws, size_t ws_size,
                              hipStream_t stream)
{
  const float* x   = (const float*)d_in[0];
  const float* W1  = (const float*)d_in[3];
  const float* b1  = (const float*)d_in[4];
  const float* W2  = (const float*)d_in[5];
  const float* b2  = (const float*)d_in[6];
  const float* Wg1 = (const float*)d_in[7];
  const float* bg1 = (const float*)d_in[8];
  const float* Wg2 = (const float*)d_in[9];
  const float* bg2 = (const float*)d_in[10];
  const float* Wf1 = (const float*)d_in[11];
  const float* bf1 = (const float*)d_in[12];
  const float* Wf2 = (const float*)d_in[13];
  const float* bf2 = (const float*)d_in[14];
  const float* Wo  = (const float*)d_in[15];
  const float* bo  = (const float*)d_in[16];
  float* out = (float*)d_out;

  float* ws = (float*)d_ws;
  float* m1 = ws;            // 2560 floats
  float* g1 = ws + 4096;     // 8192
  float* g2 = ws + 16384;    // 16384
  float* y1 = ws + 32768;    // 65536
  float* y2 = ws + 98304;    // 131072

  k_init_m1<<<10, 256, 0, stream>>>(b2, m1);
  // dominant: per-ROI 2-layer MLP, 64 r x 4 c x 2 mHalf
  k_mlp<<<512, 256, 0, stream>>>(x, W1, b1, W2, m1);
  // collapsed-GCN + FC chain
  k_fc_small<20, 1><<<32, 256, 0, stream>>>(m1, Wg1, bg1, g1, 64);
  k_fc_small<64, 1><<<64, 256, 0, stream>>>(g1, Wg2, bg2, g2, 128);
  gemm_n64<1><<<8,   256, 0, stream>>>(g2, 128,  Wf1, 512,  bf1, y1, 512, 2);
  gemm_n64<1><<<16,  256, 0, stream>>>(y1, 512,  Wf2, 1024, bf2, y2, 1024, 8);
  gemm_n64<0><<<100, 256, 0, stream>>>(y2, 1024, Wo,  6400, bo,  out, 6400, 16);
}